// Round 2
// baseline (5440.746 us; speedup 1.0000x reference)
//
#include <hip/hip_runtime.h>
#include <math.h>

// BiLSTM-CRF, fp32. V=50000 B=64 T=256 D=256 H=256 C=32
//
// R1: weight-stationary LSTM recurrence. w_hh lives in VGPRs (64 floats/thread,
// 256 WGs x 1024 threads); h exchanged between the 4 hidden-slice WGs of a
// group via device-scope atomics on a double-buffered global buffer.
//
// ws layout (floats):
//   xg   : [2][64][256][1024] input-gates (+bias)             33554432
//   hcat : [64][256][512]     h_f | h_b (b at reversed t)      8388608
//   em   : [64][256][32]      emissions                         524288
//   hx   : [2buf][64grp][2seq][256] h exchange                   65536
//   cnt  : 64 uint barrier counters
//
// d_out: float32[16448] = paths[64][256] (as float) then best_score[64]

// ---------------------------------------------------------------- K0z: zero barrier counters
__global__ void k0z_zero(unsigned int* __restrict__ cnt)
{
    if (threadIdx.x < 64) cnt[threadIdx.x] = 0u;
}

// ---------------------------------------------------------------- K1: embed + input GEMM
// xg[dir][b][t][j] = emb[tok(b,t,dir)] . w_ih[dir][j][:] + b_ih[j]+b_hh[j]
__global__ __launch_bounds__(256) void k1_xgemm(
    const int* __restrict__ sent, const int* __restrict__ lens,
    const float* __restrict__ emb,
    const float* __restrict__ wih_f, const float* __restrict__ wih_b,
    const float* __restrict__ bih_f, const float* __restrict__ bhh_f,
    const float* __restrict__ bih_b, const float* __restrict__ bhh_b,
    float* __restrict__ xg)
{
    const int bid = blockIdx.x;          // 2048 = 2 dir * 128 mt * 8 nt
    const int dir = bid >> 10;
    const int rem = bid & 1023;
    const int mt = rem >> 3, nt = rem & 7;
    const int r0 = mt * 128, j0 = nt * 128;
    const int b = r0 >> 8, t0 = r0 & 255;
    const float* __restrict__ wih = dir ? wih_b : wih_f;
    const float* __restrict__ bih = dir ? bih_b : bih_f;
    const float* __restrict__ bhh = dir ? bhh_b : bhh_f;

    __shared__ __align__(16) float At[32][132];
    __shared__ __align__(16) float Bt[32][132];
    __shared__ int tok_s[128];

    const int tid = threadIdx.x;
    if (tid < 128) {
        int t = t0 + tid;
        int tt = t;
        if (dir) { int L = lens[b]; if (t < L) tt = L - 1 - t; }
        tok_s[tid] = sent[b * 256 + tt];
    }
    __syncthreads();

    float acc[8][8];
    #pragma unroll
    for (int i = 0; i < 8; ++i)
        #pragma unroll
        for (int j = 0; j < 8; ++j) acc[i][j] = 0.f;

    const int lrow = tid >> 3;
    const int l8 = tid & 7;
    const int tx = tid & 15, ty = tid >> 4;

    for (int kc = 0; kc < 256; kc += 32) {
        #pragma unroll
        for (int it = 0; it < 4; ++it) {
            int row = lrow + it * 32;
            float4 va = *(const float4*)(emb + (size_t)tok_s[row] * 256 + kc + l8 * 4);
            At[l8*4+0][row] = va.x; At[l8*4+1][row] = va.y;
            At[l8*4+2][row] = va.z; At[l8*4+3][row] = va.w;
            float4 vb = *(const float4*)(wih + (size_t)(j0 + row) * 256 + kc + l8 * 4);
            Bt[l8*4+0][row] = vb.x; Bt[l8*4+1][row] = vb.y;
            Bt[l8*4+2][row] = vb.z; Bt[l8*4+3][row] = vb.w;
        }
        __syncthreads();
        #pragma unroll
        for (int k = 0; k < 32; ++k) {
            float4 a0 = *(const float4*)&At[k][ty*8];
            float4 a1 = *(const float4*)&At[k][ty*8+4];
            float4 b0 = *(const float4*)&Bt[k][tx*8];
            float4 b1 = *(const float4*)&Bt[k][tx*8+4];
            float av[8] = {a0.x,a0.y,a0.z,a0.w,a1.x,a1.y,a1.z,a1.w};
            float bv[8] = {b0.x,b0.y,b0.z,b0.w,b1.x,b1.y,b1.z,b1.w};
            #pragma unroll
            for (int i = 0; i < 8; ++i)
                #pragma unroll
                for (int j = 0; j < 8; ++j)
                    acc[i][j] += av[i] * bv[j];
        }
        __syncthreads();
    }

    float bias[8];
    {
        float4 p0 = *(const float4*)(bih + j0 + tx*8);
        float4 p1 = *(const float4*)(bih + j0 + tx*8 + 4);
        float4 q0 = *(const float4*)(bhh + j0 + tx*8);
        float4 q1 = *(const float4*)(bhh + j0 + tx*8 + 4);
        bias[0]=p0.x+q0.x; bias[1]=p0.y+q0.y; bias[2]=p0.z+q0.z; bias[3]=p0.w+q0.w;
        bias[4]=p1.x+q1.x; bias[5]=p1.y+q1.y; bias[6]=p1.z+q1.z; bias[7]=p1.w+q1.w;
    }
    #pragma unroll
    for (int i = 0; i < 8; ++i) {
        int r = r0 + ty*8 + i;
        int t = r & 255;
        float* orow = xg + ((size_t)(dir*64 + b) * 256 + t) * 1024 + j0 + tx*8;
        float4 o0, o1;
        o0.x = acc[i][0]+bias[0]; o0.y = acc[i][1]+bias[1];
        o0.z = acc[i][2]+bias[2]; o0.w = acc[i][3]+bias[3];
        o1.x = acc[i][4]+bias[4]; o1.y = acc[i][5]+bias[5];
        o1.z = acc[i][6]+bias[6]; o1.w = acc[i][7]+bias[7];
        *(float4*)orow = o0;
        *(float4*)(orow + 4) = o1;
    }
}

// ---------------------------------------------------------------- K2: weight-stationary LSTM
// 256 WGs = 2 dir x 32 seq-pairs x 4 slices(64 units). Thread (kg 0..7, rp 0..127):
// holds w_hh rows {2rp,2rp+1} x k-slice [kg*32,kg*32+32) in VGPRs (64 floats).
__global__ __launch_bounds__(1024) void k2_lstm(
    const float* __restrict__ whh_f, const float* __restrict__ whh_b,
    const float* __restrict__ xg, float* __restrict__ hcat,
    float* __restrict__ hx, unsigned int* __restrict__ cnt)
{
    const int wg = blockIdx.x;           // 256
    const int dir = wg >> 7;
    const int sp  = (wg >> 2) & 31;
    const int slice = wg & 3;
    const int grp = wg >> 2;             // 64 groups of 4 slice-WGs
    const float* __restrict__ w = dir ? whh_b : whh_f;
    const int b0 = sp * 2;

    const int tid = threadIdx.x;
    const int kg = tid >> 7;             // 0..7 (wave-uniform)
    const int rp = tid & 127;
    const int r0 = rp * 2;
    const int gate = r0 >> 6;            // 0..3 (i,f,g,o)
    const int j0 = gate * 256 + slice * 64 + (r0 & 63);
    const int kbase = kg * 32;

    // ---- weights to VGPRs (one-time)
    float4 wr0[8], wr1[8];
    {
        const float* wp0 = w + (size_t)j0 * 256 + kbase;
        const float* wp1 = wp0 + 256;
        #pragma unroll
        for (int i = 0; i < 8; ++i) {
            wr0[i] = *(const float4*)(wp0 + i * 4);
            wr1[i] = *(const float4*)(wp1 + i * 4);
        }
    }

    __shared__ __align__(16) float hs[2][256];
    __shared__ float cs[2][64];
    __shared__ __align__(16) float red[8][2][256];
    __shared__ float gsum[2][256];

    if (tid < 512) hs[tid >> 8][tid & 255] = 0.f;
    if (tid < 128) cs[tid >> 6][tid & 63] = 0.f;

    // phase-B mapping (tid<512)
    const int s_b = tid >> 8, r_b = tid & 255;
    const int jb = (r_b >> 6) * 256 + slice * 64 + (r_b & 63);
    const float* xgp = xg + (size_t)(dir * 64 + b0 + s_b) * 262144 + jb;
    // phase-C mapping (tid<128)
    const int s_c = tid >> 6, ul = tid & 63;
    float* hco = hcat + (size_t)(b0 + s_c) * 131072 + dir * 256 + slice * 64 + ul;
    float* hxw = hx + ((size_t)grp * 2 + s_c) * 256 + slice * 64 + ul;   // + buf*32768
    // phase-D mapping (tid<512)
    const float* hxr = hx + (size_t)grp * 512 + s_b * 256 + r_b;         // + buf*32768

    __syncthreads();

    for (int t = 0; t < 256; ++t) {
        // prefetch xg gate value for phase B (covered by phase-A latency)
        float xpre = 0.f;
        if (tid < 512) xpre = xgp[(size_t)t * 1024];

        // ---- phase A: partial gates from register-resident weights
        float2 a00 = {0.f,0.f}, a01 = {0.f,0.f}, a10 = {0.f,0.f}, a11 = {0.f,0.f};
        #pragma unroll
        for (int i = 0; i < 8; ++i) {
            float4 ha = *(const float4*)&hs[0][kbase + i * 4];   // broadcast
            float4 hb = *(const float4*)&hs[1][kbase + i * 4];
            float4 wa = wr0[i], wb = wr1[i];
            a00.x += wa.x*ha.x; a00.y += wa.y*ha.y; a00.x += wa.z*ha.z; a00.y += wa.w*ha.w;
            a01.x += wa.x*hb.x; a01.y += wa.y*hb.y; a01.x += wa.z*hb.z; a01.y += wa.w*hb.w;
            a10.x += wb.x*ha.x; a10.y += wb.y*ha.y; a10.x += wb.z*ha.z; a10.y += wb.w*ha.w;
            a11.x += wb.x*hb.x; a11.y += wb.y*hb.y; a11.x += wb.z*hb.z; a11.y += wb.w*hb.w;
        }
        *(float2*)&red[kg][0][r0] = make_float2(a00.x + a00.y, a10.x + a10.y);
        *(float2*)&red[kg][1][r0] = make_float2(a01.x + a01.y, a11.x + a11.y);
        __syncthreads();

        // ---- phase B: k-reduction + xg
        if (tid < 512) {
            float g = xpre;
            #pragma unroll
            for (int kk = 0; kk < 8; ++kk) g += red[kk][s_b][r_b];
            gsum[s_b][r_b] = g;
        }
        __syncthreads();

        // ---- phase C: cell update for own 64 units x 2 seqs
        if (tid < 128) {
            float gi = gsum[s_c][ul];
            float gf = gsum[s_c][64 + ul];
            float gg = gsum[s_c][128 + ul];
            float go = gsum[s_c][192 + ul];
            float si = 1.f / (1.f + expf(-gi));
            float sf = 1.f / (1.f + expf(-gf));
            float so = 1.f / (1.f + expf(-go));
            float cn = sf * cs[s_c][ul] + si * tanhf(gg);
            float hn = so * tanhf(cn);
            cs[s_c][ul] = cn;
            hs[s_c][slice * 64 + ul] = hn;
            hco[(size_t)t * 512] = hn;
            __hip_atomic_store(hxw + (t & 1) * 32768, hn,
                               __ATOMIC_RELAXED, __HIP_MEMORY_SCOPE_AGENT);
        }
        __syncthreads();

        // ---- group barrier (4 slice-WGs)
        if (tid == 0) {
            __threadfence();
            __hip_atomic_fetch_add(&cnt[grp], 1u, __ATOMIC_RELEASE, __HIP_MEMORY_SCOPE_AGENT);
            const unsigned tgt = 4u * (unsigned)(t + 1);
            while (__hip_atomic_load(&cnt[grp], __ATOMIC_ACQUIRE, __HIP_MEMORY_SCOPE_AGENT) < tgt)
                __builtin_amdgcn_s_sleep(1);
            __threadfence();
        }
        __syncthreads();

        // ---- phase D: gather full h for next step
        if (tid < 512)
            hs[s_b][r_b] = __hip_atomic_load(hxr + (t & 1) * 32768,
                                             __ATOMIC_RELAXED, __HIP_MEMORY_SCOPE_AGENT);
        __syncthreads();
    }
}

// ---------------------------------------------------------------- K3: emissions
__global__ __launch_bounds__(256) void k3_emis(
    const float* __restrict__ hcat, const float* __restrict__ wout,
    const float* __restrict__ bout, const int* __restrict__ lens,
    float* __restrict__ em)
{
    const int b = blockIdx.x >> 3;
    const int tt0 = (blockIdx.x & 7) * 32;
    __shared__ float wsw[512 * 32];
    const int tid = threadIdx.x;
    for (int i = tid; i < 16384; i += 256) {
        int c_ = i >> 9, k_ = i & 511;
        wsw[k_ * 32 + ((k_ + c_) & 31)] = wout[i];
    }
    __syncthreads();
    const int c = tid & 31, tq = tid >> 5;
    const int L = lens[b];
    float acc[4];
    const float* hfp[4];
    const float* hbp[4];
    int tv[4];
    #pragma unroll
    for (int i = 0; i < 4; ++i) {
        int t = tt0 + i * 8 + tq;
        tv[i] = t;
        int tr = (t < L) ? (L - 1 - t) : t;
        hfp[i] = hcat + ((size_t)b * 256 + t) * 512;
        hbp[i] = hcat + ((size_t)b * 256 + tr) * 512 + 256;
        acc[i] = bout[c];
    }
    for (int k = 0; k < 256; k += 4) {
        float w0 = wsw[(k+0)*32 + ((k+0+c)&31)];
        float w1 = wsw[(k+1)*32 + ((k+1+c)&31)];
        float w2_ = wsw[(k+2)*32 + ((k+2+c)&31)];
        float w3 = wsw[(k+3)*32 + ((k+3+c)&31)];
        #pragma unroll
        for (int i = 0; i < 4; ++i) {
            float4 h = *(const float4*)(hfp[i] + k);
            acc[i] += h.x*w0 + h.y*w1 + h.z*w2_ + h.w*w3;
        }
        float v0 = wsw[(256+k+0)*32 + ((256+k+0+c)&31)];
        float v1 = wsw[(256+k+1)*32 + ((256+k+1+c)&31)];
        float v2 = wsw[(256+k+2)*32 + ((256+k+2+c)&31)];
        float v3 = wsw[(256+k+3)*32 + ((256+k+3+c)&31)];
        #pragma unroll
        for (int i = 0; i < 4; ++i) {
            float4 h = *(const float4*)(hbp[i] + k);
            acc[i] += h.x*v0 + h.y*v1 + h.z*v2 + h.w*v3;
        }
    }
    #pragma unroll
    for (int i = 0; i < 4; ++i)
        em[((size_t)b * 256 + tv[i]) * 32 + c] = acc[i];
}

// ---------------------------------------------------------------- K4: Viterbi fwd + backtrace
__global__ __launch_bounds__(256) void k4_viterbi(
    const float* __restrict__ em, const int* __restrict__ lens,
    const float* __restrict__ strans, const float* __restrict__ etrans,
    const float* __restrict__ trans, float* __restrict__ out)
{
    const int b = blockIdx.x;
    __shared__ float em_s[8192];
    __shared__ float trans_t[32 * 33];
    __shared__ float score_s[32];
    __shared__ float fin[32];
    __shared__ unsigned char hist[256][32];
    __shared__ unsigned char path[256];
    __shared__ float bs_s;
    const int tid = threadIdx.x;
    for (int i = tid; i < 8192; i += 256) em_s[i] = em[(size_t)b * 8192 + i];
    for (int i = tid; i < 1024; i += 256) {
        int p = i >> 5, cc = i & 31;
        trans_t[cc * 33 + p] = trans[i];
    }
    __syncthreads();
    if (tid < 32) score_s[tid] = strans[tid] + em_s[tid];
    __syncthreads();
    const int c = tid >> 3, pg = tid & 7;
    const int L = lens[b];
    for (int t = 1; t < 256; ++t) {
        float v = -1e30f; int bi = 0;
        #pragma unroll
        for (int i = 0; i < 4; ++i) {
            int p = pg * 4 + i;
            float cand = score_s[p] + trans_t[c * 33 + p];
            if (cand > v) { v = cand; bi = p; }
        }
        #pragma unroll
        for (int off = 4; off >= 1; off >>= 1) {
            float ov = __shfl_down(v, off);
            int oi = __shfl_down(bi, off);
            if (ov > v) { v = ov; bi = oi; }
        }
        float ns = 0.f;
        if (pg == 0) {
            hist[t][c] = (unsigned char)bi;
            ns = (t < L) ? (v + em_s[t * 32 + c]) : score_s[c];
        }
        __syncthreads();
        if (pg == 0) score_s[c] = ns;
        __syncthreads();
    }
    if (tid < 32) fin[tid] = score_s[tid] + etrans[tid];
    __syncthreads();
    if (tid == 0) {
        float bv = -1e30f; int bl = 0;
        for (int cc = 0; cc < 32; ++cc)
            if (fin[cc] > bv) { bv = fin[cc]; bl = cc; }
        bs_s = bv;
        int tag = bl;
        path[255] = (unsigned char)tag;
        for (int t = 254; t >= 0; --t) {
            if (t < L - 1) tag = hist[t + 1][tag];
            path[t] = (unsigned char)tag;
        }
    }
    __syncthreads();
    out[(size_t)b * 256 + tid] = (float)path[tid];
    if (tid == 0) out[16384 + b] = bs_s;
}

// ---------------------------------------------------------------- launch
extern "C" void kernel_launch(void* const* d_in, const int* in_sizes, int n_in,
                              void* d_out, int out_size, void* d_ws, size_t ws_size,
                              hipStream_t stream)
{
    const int*   sent   = (const int*)  d_in[0];
    const int*   lens   = (const int*)  d_in[1];
    const float* emb    = (const float*)d_in[2];
    const float* wih_f  = (const float*)d_in[3];
    const float* whh_f  = (const float*)d_in[4];
    const float* bih_f  = (const float*)d_in[5];
    const float* bhh_f  = (const float*)d_in[6];
    const float* wih_b  = (const float*)d_in[7];
    const float* whh_b  = (const float*)d_in[8];
    const float* bih_b  = (const float*)d_in[9];
    const float* bhh_b  = (const float*)d_in[10];
    const float* wout   = (const float*)d_in[11];
    const float* bout   = (const float*)d_in[12];
    const float* strans = (const float*)d_in[13];
    const float* etrans = (const float*)d_in[14];
    const float* trans  = (const float*)d_in[15];
    float* out = (float*)d_out;

    float* ws   = (float*)d_ws;
    float* xg   = ws;                       // 33554432
    float* hcat = xg + 33554432;            // 8388608
    float* em   = hcat + 8388608;           // 524288
    float* hx   = em + 524288;              // 65536
    unsigned int* cnt = (unsigned int*)(hx + 65536);  // 64

    hipLaunchKernelGGL(k0z_zero, dim3(1), dim3(64), 0, stream, cnt);
    hipLaunchKernelGGL(k1_xgemm, dim3(2048), dim3(256), 0, stream,
                       sent, lens, emb, wih_f, wih_b, bih_f, bhh_f, bih_b, bhh_b, xg);
    hipLaunchKernelGGL(k2_lstm, dim3(256), dim3(1024), 0, stream,
                       whh_f, whh_b, xg, hcat, hx, cnt);
    hipLaunchKernelGGL(k3_emis, dim3(512), dim3(256), 0, stream,
                       hcat, wout, bout, lens, em);
    hipLaunchKernelGGL(k4_viterbi, dim3(64), dim3(256), 0, stream,
                       em, lens, strans, etrans, trans, out);
}

// Round 3
// 2320.708 us; speedup vs baseline: 2.3444x; 2.3444x over previous
//
#include <hip/hip_runtime.h>
#include <math.h>

// BiLSTM-CRF, fp32. V=50000 B=64 T=256 D=256 H=256 C=32
//
// R2: weight-stationary LSTM, VGPR-pinned via volatile loads; 4-WG groups
// swizzled onto one XCD; flag-based release/acquire exchange (no threadfence,
// padded per-member flag lines, hcat store off critical path).
//
// ws layout (floats):
//   xg    : [2][64][256][1024]          33554432
//   hcat  : [64][256][512]               8388608
//   em    : [64][256][32]                 524288
//   hx    : [2buf][64grp][2seq][256]       65536
//   flags : [64grp][4mem][16pad] uint       4096
//
// d_out: float32[16448] = paths[64][256] (as float) then best_score[64]

typedef unsigned long long ull;

// ---------------------------------------------------------------- K0z: zero flags
__global__ void k0z_zero(unsigned int* __restrict__ flags)
{
    int i = blockIdx.x * 1024 + threadIdx.x;
    if (i < 4096) flags[i] = 0u;
}

// ---------------------------------------------------------------- K1: embed + input GEMM
__global__ __launch_bounds__(256) void k1_xgemm(
    const int* __restrict__ sent, const int* __restrict__ lens,
    const float* __restrict__ emb,
    const float* __restrict__ wih_f, const float* __restrict__ wih_b,
    const float* __restrict__ bih_f, const float* __restrict__ bhh_f,
    const float* __restrict__ bih_b, const float* __restrict__ bhh_b,
    float* __restrict__ xg)
{
    const int bid = blockIdx.x;          // 2048 = 2 dir * 128 mt * 8 nt
    const int dir = bid >> 10;
    const int rem = bid & 1023;
    const int mt = rem >> 3, nt = rem & 7;
    const int r0 = mt * 128, j0 = nt * 128;
    const int b = r0 >> 8, t0 = r0 & 255;
    const float* __restrict__ wih = dir ? wih_b : wih_f;
    const float* __restrict__ bih = dir ? bih_b : bih_f;
    const float* __restrict__ bhh = dir ? bhh_b : bhh_f;

    __shared__ __align__(16) float At[32][132];
    __shared__ __align__(16) float Bt[32][132];
    __shared__ int tok_s[128];

    const int tid = threadIdx.x;
    if (tid < 128) {
        int t = t0 + tid;
        int tt = t;
        if (dir) { int L = lens[b]; if (t < L) tt = L - 1 - t; }
        tok_s[tid] = sent[b * 256 + tt];
    }
    __syncthreads();

    float acc[8][8];
    #pragma unroll
    for (int i = 0; i < 8; ++i)
        #pragma unroll
        for (int j = 0; j < 8; ++j) acc[i][j] = 0.f;

    const int lrow = tid >> 3;
    const int l8 = tid & 7;
    const int tx = tid & 15, ty = tid >> 4;

    for (int kc = 0; kc < 256; kc += 32) {
        #pragma unroll
        for (int it = 0; it < 4; ++it) {
            int row = lrow + it * 32;
            float4 va = *(const float4*)(emb + (size_t)tok_s[row] * 256 + kc + l8 * 4);
            At[l8*4+0][row] = va.x; At[l8*4+1][row] = va.y;
            At[l8*4+2][row] = va.z; At[l8*4+3][row] = va.w;
            float4 vb = *(const float4*)(wih + (size_t)(j0 + row) * 256 + kc + l8 * 4);
            Bt[l8*4+0][row] = vb.x; Bt[l8*4+1][row] = vb.y;
            Bt[l8*4+2][row] = vb.z; Bt[l8*4+3][row] = vb.w;
        }
        __syncthreads();
        #pragma unroll
        for (int k = 0; k < 32; ++k) {
            float4 a0 = *(const float4*)&At[k][ty*8];
            float4 a1 = *(const float4*)&At[k][ty*8+4];
            float4 b0 = *(const float4*)&Bt[k][tx*8];
            float4 b1 = *(const float4*)&Bt[k][tx*8+4];
            float av[8] = {a0.x,a0.y,a0.z,a0.w,a1.x,a1.y,a1.z,a1.w};
            float bv[8] = {b0.x,b0.y,b0.z,b0.w,b1.x,b1.y,b1.z,b1.w};
            #pragma unroll
            for (int i = 0; i < 8; ++i)
                #pragma unroll
                for (int j = 0; j < 8; ++j)
                    acc[i][j] += av[i] * bv[j];
        }
        __syncthreads();
    }

    float bias[8];
    {
        float4 p0 = *(const float4*)(bih + j0 + tx*8);
        float4 p1 = *(const float4*)(bih + j0 + tx*8 + 4);
        float4 q0 = *(const float4*)(bhh + j0 + tx*8);
        float4 q1 = *(const float4*)(bhh + j0 + tx*8 + 4);
        bias[0]=p0.x+q0.x; bias[1]=p0.y+q0.y; bias[2]=p0.z+q0.z; bias[3]=p0.w+q0.w;
        bias[4]=p1.x+q1.x; bias[5]=p1.y+q1.y; bias[6]=p1.z+q1.z; bias[7]=p1.w+q1.w;
    }
    #pragma unroll
    for (int i = 0; i < 8; ++i) {
        int r = r0 + ty*8 + i;
        int t = r & 255;
        float* orow = xg + ((size_t)(dir*64 + b) * 256 + t) * 1024 + j0 + tx*8;
        float4 o0, o1;
        o0.x = acc[i][0]+bias[0]; o0.y = acc[i][1]+bias[1];
        o0.z = acc[i][2]+bias[2]; o0.w = acc[i][3]+bias[3];
        o1.x = acc[i][4]+bias[4]; o1.y = acc[i][5]+bias[5];
        o1.z = acc[i][6]+bias[6]; o1.w = acc[i][7]+bias[7];
        *(float4*)orow = o0;
        *(float4*)(orow + 4) = o1;
    }
}

// ---------------------------------------------------------------- K2: weight-stationary LSTM
// 256 WGs: member m = blockIdx>>6 (hidden slice), group g = blockIdx&63.
// Members of a group sit at blockIdx {g,64+g,128+g,192+g} == g (mod 8) -> same XCD.
// Thread (kg=tid>>7, rp=tid&127) holds w_hh rows {2rp,2rp+1} x k[kg*32,+32) in VGPRs.
__global__ __launch_bounds__(1024, 4) void k2_lstm(
    const float* __restrict__ whh_f, const float* __restrict__ whh_b,
    const float* __restrict__ xg, float* __restrict__ hcat,
    float* __restrict__ hx, unsigned int* __restrict__ flags)
{
    const int m = blockIdx.x >> 6;       // slice / member 0..3
    const int g = blockIdx.x & 63;       // group
    const int dir = g >> 5;
    const int b0 = (g & 31) * 2;
    const float* __restrict__ w = dir ? whh_b : whh_f;

    const int tid = threadIdx.x;
    const int kg = tid >> 7;             // 0..7, wave-uniform
    const int rp = tid & 127;
    const int r0 = rp * 2;
    const int gate = r0 >> 6;            // 0..3
    const int j0 = gate * 256 + m * 64 + (r0 & 63);
    const int kbase = kg * 32;

    // ---- weights to VGPRs, pinned: volatile scalar loads cannot be re-executed
    float w0[32], w1[32];
    {
        const volatile float* wp0 = w + (size_t)j0 * 256 + kbase;
        const volatile float* wp1 = wp0 + 256;
        #pragma unroll
        for (int i = 0; i < 32; ++i) { w0[i] = wp0[i]; w1[i] = wp1[i]; }
    }

    __shared__ __align__(16) float hs[2][256];
    __shared__ float cs[2][64];
    __shared__ __align__(16) float red[8][2][256];
    __shared__ float gsum[2][256];

    if (tid < 512) hs[tid >> 8][tid & 255] = 0.f;
    if (tid < 128) cs[tid >> 6][tid & 63] = 0.f;

    // phase-B mapping (tid<512)
    const int s_b = tid >> 8, r_b = tid & 255;
    const int jb = (r_b >> 6) * 256 + m * 64 + (r_b & 63);
    const float* xgp = xg + (size_t)(dir * 64 + b0 + s_b) * 262144 + jb;
    // phase-C mapping (tid<128)
    const int s_c = tid >> 6, ul = tid & 63;
    float* hx_w = hx + ((size_t)g * 2 + s_c) * 256 + m * 64 + ul;      // + buf*32768
    // loader mapping (tid<256)
    const int s_r = tid >> 7, pr = tid & 127;
    const ull* hx_r = (const ull*)hx + ((size_t)g * 2 + s_r) * 128 + pr; // + buf*16384
    float* hc_r = hcat + (((size_t)(b0 + s_r) * 256) * 512) + dir * 256 + 2 * pr;
    unsigned int* myflag = flags + ((size_t)g * 4 + m) * 16;

    __syncthreads();

    for (int t = 0; t < 256; ++t) {
        float xpre = 0.f;
        if (tid < 512) xpre = xgp[(size_t)t * 1024];

        // ---- phase A: partial gates from register-resident weights
        float a00 = 0.f, a01 = 0.f, a10 = 0.f, a11 = 0.f;
        #pragma unroll
        for (int i = 0; i < 8; ++i) {
            float4 ha = *(const float4*)&hs[0][kbase + i * 4];   // broadcast read
            float4 hb = *(const float4*)&hs[1][kbase + i * 4];
            const float* W0 = &w0[i * 4];
            const float* W1 = &w1[i * 4];
            a00 += W0[0]*ha.x + W0[1]*ha.y + W0[2]*ha.z + W0[3]*ha.w;
            a01 += W0[0]*hb.x + W0[1]*hb.y + W0[2]*hb.z + W0[3]*hb.w;
            a10 += W1[0]*ha.x + W1[1]*ha.y + W1[2]*ha.z + W1[3]*ha.w;
            a11 += W1[0]*hb.x + W1[1]*hb.y + W1[2]*hb.z + W1[3]*hb.w;
        }
        *(float2*)&red[kg][0][r0] = make_float2(a00, a10);
        *(float2*)&red[kg][1][r0] = make_float2(a01, a11);
        __syncthreads();                                  // (1)

        // ---- phase B: k-reduction + xg
        if (tid < 512) {
            float gv = xpre;
            #pragma unroll
            for (int kk = 0; kk < 8; ++kk) gv += red[kk][s_b][r_b];
            gsum[s_b][r_b] = gv;
        }
        __syncthreads();                                  // (2)

        // ---- phase C: cell update + publish own slice
        if (tid < 128) {
            float gi = gsum[s_c][ul];
            float gf = gsum[s_c][64 + ul];
            float gg = gsum[s_c][128 + ul];
            float go = gsum[s_c][192 + ul];
            float si = 1.f / (1.f + expf(-gi));
            float sf = 1.f / (1.f + expf(-gf));
            float so = 1.f / (1.f + expf(-go));
            float cn = sf * cs[s_c][ul] + si * tanhf(gg);
            float hn = so * tanhf(cn);
            cs[s_c][ul] = cn;
            hs[s_c][m * 64 + ul] = hn;
            __hip_atomic_store(hx_w + (t & 1) * 32768, hn,
                               __ATOMIC_RELAXED, __HIP_MEMORY_SCOPE_AGENT);
        }
        __syncthreads();                                  // (3) drains hx stores (vmcnt 0)

        // ---- flag publish + 3-way spin (all in wave 0)
        if (tid == 0)
            __hip_atomic_store(myflag, (unsigned)(t + 1),
                               __ATOMIC_RELEASE, __HIP_MEMORY_SCOPE_AGENT);
        if (tid < 4 && tid != m) {
            const unsigned int* pf = flags + ((size_t)g * 4 + tid) * 16;
            while (__hip_atomic_load(pf, __ATOMIC_ACQUIRE, __HIP_MEMORY_SCOPE_AGENT)
                   < (unsigned)(t + 1)) {}
        }
        __syncthreads();                                  // (4)

        // ---- loader: gather full h, write hs + hcat (hcat off critical path)
        if (tid < 256) {
            ull dv = __hip_atomic_load(hx_r + (t & 1) * 16384,
                                       __ATOMIC_RELAXED, __HIP_MEMORY_SCOPE_AGENT);
            union { ull u; float2 f; } cv; cv.u = dv;
            *(float2*)&hs[s_r][2 * pr] = cv.f;
            *(float2*)(hc_r + (size_t)t * 512) = cv.f;
        }
        __syncthreads();                                  // (5)
    }
}

// ---------------------------------------------------------------- K3: emissions
__global__ __launch_bounds__(256) void k3_emis(
    const float* __restrict__ hcat, const float* __restrict__ wout,
    const float* __restrict__ bout, const int* __restrict__ lens,
    float* __restrict__ em)
{
    const int b = blockIdx.x >> 3;
    const int tt0 = (blockIdx.x & 7) * 32;
    __shared__ float wsw[512 * 32];
    const int tid = threadIdx.x;
    for (int i = tid; i < 16384; i += 256) {
        int c_ = i >> 9, k_ = i & 511;
        wsw[k_ * 32 + ((k_ + c_) & 31)] = wout[i];
    }
    __syncthreads();
    const int c = tid & 31, tq = tid >> 5;
    const int L = lens[b];
    float acc[4];
    const float* hfp[4];
    const float* hbp[4];
    int tv[4];
    #pragma unroll
    for (int i = 0; i < 4; ++i) {
        int t = tt0 + i * 8 + tq;
        tv[i] = t;
        int tr = (t < L) ? (L - 1 - t) : t;
        hfp[i] = hcat + ((size_t)b * 256 + t) * 512;
        hbp[i] = hcat + ((size_t)b * 256 + tr) * 512 + 256;
        acc[i] = bout[c];
    }
    for (int k = 0; k < 256; k += 4) {
        float w0 = wsw[(k+0)*32 + ((k+0+c)&31)];
        float w1 = wsw[(k+1)*32 + ((k+1+c)&31)];
        float w2_ = wsw[(k+2)*32 + ((k+2+c)&31)];
        float w3 = wsw[(k+3)*32 + ((k+3+c)&31)];
        #pragma unroll
        for (int i = 0; i < 4; ++i) {
            float4 h = *(const float4*)(hfp[i] + k);
            acc[i] += h.x*w0 + h.y*w1 + h.z*w2_ + h.w*w3;
        }
        float v0 = wsw[(256+k+0)*32 + ((256+k+0+c)&31)];
        float v1 = wsw[(256+k+1)*32 + ((256+k+1+c)&31)];
        float v2 = wsw[(256+k+2)*32 + ((256+k+2+c)&31)];
        float v3 = wsw[(256+k+3)*32 + ((256+k+3+c)&31)];
        #pragma unroll
        for (int i = 0; i < 4; ++i) {
            float4 h = *(const float4*)(hbp[i] + k);
            acc[i] += h.x*v0 + h.y*v1 + h.z*v2 + h.w*v3;
        }
    }
    #pragma unroll
    for (int i = 0; i < 4; ++i)
        em[((size_t)b * 256 + tv[i]) * 32 + c] = acc[i];
}

// ---------------------------------------------------------------- K4: Viterbi fwd + backtrace
__global__ __launch_bounds__(256) void k4_viterbi(
    const float* __restrict__ em, const int* __restrict__ lens,
    const float* __restrict__ strans, const float* __restrict__ etrans,
    const float* __restrict__ trans, float* __restrict__ out)
{
    const int b = blockIdx.x;
    __shared__ float em_s[8192];
    __shared__ float trans_t[32 * 33];
    __shared__ float score_s[32];
    __shared__ float fin[32];
    __shared__ unsigned char hist[256][32];
    __shared__ unsigned char path[256];
    __shared__ float bs_s;
    const int tid = threadIdx.x;
    for (int i = tid; i < 8192; i += 256) em_s[i] = em[(size_t)b * 8192 + i];
    for (int i = tid; i < 1024; i += 256) {
        int p = i >> 5, cc = i & 31;
        trans_t[cc * 33 + p] = trans[i];
    }
    __syncthreads();
    if (tid < 32) score_s[tid] = strans[tid] + em_s[tid];
    __syncthreads();
    const int c = tid >> 3, pg = tid & 7;
    const int L = lens[b];
    for (int t = 1; t < 256; ++t) {
        float v = -1e30f; int bi = 0;
        #pragma unroll
        for (int i = 0; i < 4; ++i) {
            int p = pg * 4 + i;
            float cand = score_s[p] + trans_t[c * 33 + p];
            if (cand > v) { v = cand; bi = p; }
        }
        #pragma unroll
        for (int off = 4; off >= 1; off >>= 1) {
            float ov = __shfl_down(v, off);
            int oi = __shfl_down(bi, off);
            if (ov > v) { v = ov; bi = oi; }
        }
        float ns = 0.f;
        if (pg == 0) {
            hist[t][c] = (unsigned char)bi;
            ns = (t < L) ? (v + em_s[t * 32 + c]) : score_s[c];
        }
        __syncthreads();
        if (pg == 0) score_s[c] = ns;
        __syncthreads();
    }
    if (tid < 32) fin[tid] = score_s[tid] + etrans[tid];
    __syncthreads();
    if (tid == 0) {
        float bv = -1e30f; int bl = 0;
        for (int cc = 0; cc < 32; ++cc)
            if (fin[cc] > bv) { bv = fin[cc]; bl = cc; }
        bs_s = bv;
        int tag = bl;
        path[255] = (unsigned char)tag;
        for (int t = 254; t >= 0; --t) {
            if (t < L - 1) tag = hist[t + 1][tag];
            path[t] = (unsigned char)tag;
        }
    }
    __syncthreads();
    out[(size_t)b * 256 + tid] = (float)path[tid];
    if (tid == 0) out[16384 + b] = bs_s;
}

// ---------------------------------------------------------------- launch
extern "C" void kernel_launch(void* const* d_in, const int* in_sizes, int n_in,
                              void* d_out, int out_size, void* d_ws, size_t ws_size,
                              hipStream_t stream)
{
    const int*   sent   = (const int*)  d_in[0];
    const int*   lens   = (const int*)  d_in[1];
    const float* emb    = (const float*)d_in[2];
    const float* wih_f  = (const float*)d_in[3];
    const float* whh_f  = (const float*)d_in[4];
    const float* bih_f  = (const float*)d_in[5];
    const float* bhh_f  = (const float*)d_in[6];
    const float* wih_b  = (const float*)d_in[7];
    const float* whh_b  = (const float*)d_in[8];
    const float* bih_b  = (const float*)d_in[9];
    const float* bhh_b  = (const float*)d_in[10];
    const float* wout   = (const float*)d_in[11];
    const float* bout   = (const float*)d_in[12];
    const float* strans = (const float*)d_in[13];
    const float* etrans = (const float*)d_in[14];
    const float* trans  = (const float*)d_in[15];
    float* out = (float*)d_out;

    float* ws   = (float*)d_ws;
    float* xg   = ws;                        // 33554432
    float* hcat = xg + 33554432;             // 8388608
    float* em   = hcat + 8388608;            // 524288
    float* hx   = em + 524288;               // 65536
    unsigned int* flags = (unsigned int*)(hx + 65536);  // 4096

    hipLaunchKernelGGL(k0z_zero, dim3(4), dim3(1024), 0, stream, flags);
    hipLaunchKernelGGL(k1_xgemm, dim3(2048), dim3(256), 0, stream,
                       sent, lens, emb, wih_f, wih_b, bih_f, bhh_f, bih_b, bhh_b, xg);
    hipLaunchKernelGGL(k2_lstm, dim3(256), dim3(1024), 0, stream,
                       whh_f, whh_b, xg, hcat, hx, flags);
    hipLaunchKernelGGL(k3_emis, dim3(512), dim3(256), 0, stream,
                       hcat, wout, bout, lens, em);
    hipLaunchKernelGGL(k4_viterbi, dim3(64), dim3(256), 0, stream,
                       em, lens, strans, etrans, trans, out);
}

// Round 4
// 1483.149 us; speedup vs baseline: 3.6684x; 1.5647x over previous
//
#include <hip/hip_runtime.h>
#include <math.h>

// BiLSTM-CRF, fp32. V=50000 B=64 T=256 D=256 H=256 C=32
//
// R3: weight-stationary LSTM; weights pinned in VGPRs via amdgpu_waves_per_eu(4,4)
// + asm value barriers (R1 remat / R2 scratch-spill both defeated the pin).
// 4 barriers/step; hcat store hidden in spin window on idle waves.
//
// ws layout (floats):
//   xg    : [2][64][256][1024]          33554432
//   hcat  : [64][256][512]               8388608
//   em    : [64][256][32]                 524288
//   hx    : [2buf][64grp][2seq][256]       65536
//   flags : [64grp][4mem][16pad] uint       4096
//
// d_out: float32[16448] = paths[64][256] (as float) then best_score[64]

typedef unsigned long long ull;

// ---------------------------------------------------------------- K0z: zero flags
__global__ void k0z_zero(unsigned int* __restrict__ flags)
{
    int i = blockIdx.x * 1024 + threadIdx.x;
    if (i < 4096) flags[i] = 0u;
}

// ---------------------------------------------------------------- K1: embed + input GEMM
__global__ __launch_bounds__(256) void k1_xgemm(
    const int* __restrict__ sent, const int* __restrict__ lens,
    const float* __restrict__ emb,
    const float* __restrict__ wih_f, const float* __restrict__ wih_b,
    const float* __restrict__ bih_f, const float* __restrict__ bhh_f,
    const float* __restrict__ bih_b, const float* __restrict__ bhh_b,
    float* __restrict__ xg)
{
    const int bid = blockIdx.x;          // 2048 = 2 dir * 128 mt * 8 nt
    const int dir = bid >> 10;
    const int rem = bid & 1023;
    const int mt = rem >> 3, nt = rem & 7;
    const int r0 = mt * 128, j0 = nt * 128;
    const int b = r0 >> 8, t0 = r0 & 255;
    const float* __restrict__ wih = dir ? wih_b : wih_f;
    const float* __restrict__ bih = dir ? bih_b : bih_f;
    const float* __restrict__ bhh = dir ? bhh_b : bhh_f;

    __shared__ __align__(16) float At[32][132];
    __shared__ __align__(16) float Bt[32][132];
    __shared__ int tok_s[128];

    const int tid = threadIdx.x;
    if (tid < 128) {
        int t = t0 + tid;
        int tt = t;
        if (dir) { int L = lens[b]; if (t < L) tt = L - 1 - t; }
        tok_s[tid] = sent[b * 256 + tt];
    }
    __syncthreads();

    float acc[8][8];
    #pragma unroll
    for (int i = 0; i < 8; ++i)
        #pragma unroll
        for (int j = 0; j < 8; ++j) acc[i][j] = 0.f;

    const int lrow = tid >> 3;
    const int l8 = tid & 7;
    const int tx = tid & 15, ty = tid >> 4;

    for (int kc = 0; kc < 256; kc += 32) {
        #pragma unroll
        for (int it = 0; it < 4; ++it) {
            int row = lrow + it * 32;
            float4 va = *(const float4*)(emb + (size_t)tok_s[row] * 256 + kc + l8 * 4);
            At[l8*4+0][row] = va.x; At[l8*4+1][row] = va.y;
            At[l8*4+2][row] = va.z; At[l8*4+3][row] = va.w;
            float4 vb = *(const float4*)(wih + (size_t)(j0 + row) * 256 + kc + l8 * 4);
            Bt[l8*4+0][row] = vb.x; Bt[l8*4+1][row] = vb.y;
            Bt[l8*4+2][row] = vb.z; Bt[l8*4+3][row] = vb.w;
        }
        __syncthreads();
        #pragma unroll
        for (int k = 0; k < 32; ++k) {
            float4 a0 = *(const float4*)&At[k][ty*8];
            float4 a1 = *(const float4*)&At[k][ty*8+4];
            float4 b0 = *(const float4*)&Bt[k][tx*8];
            float4 b1 = *(const float4*)&Bt[k][tx*8+4];
            float av[8] = {a0.x,a0.y,a0.z,a0.w,a1.x,a1.y,a1.z,a1.w};
            float bv[8] = {b0.x,b0.y,b0.z,b0.w,b1.x,b1.y,b1.z,b1.w};
            #pragma unroll
            for (int i = 0; i < 8; ++i)
                #pragma unroll
                for (int j = 0; j < 8; ++j)
                    acc[i][j] += av[i] * bv[j];
        }
        __syncthreads();
    }

    float bias[8];
    {
        float4 p0 = *(const float4*)(bih + j0 + tx*8);
        float4 p1 = *(const float4*)(bih + j0 + tx*8 + 4);
        float4 q0 = *(const float4*)(bhh + j0 + tx*8);
        float4 q1 = *(const float4*)(bhh + j0 + tx*8 + 4);
        bias[0]=p0.x+q0.x; bias[1]=p0.y+q0.y; bias[2]=p0.z+q0.z; bias[3]=p0.w+q0.w;
        bias[4]=p1.x+q1.x; bias[5]=p1.y+q1.y; bias[6]=p1.z+q1.z; bias[7]=p1.w+q1.w;
    }
    #pragma unroll
    for (int i = 0; i < 8; ++i) {
        int r = r0 + ty*8 + i;
        int t = r & 255;
        float* orow = xg + ((size_t)(dir*64 + b) * 256 + t) * 1024 + j0 + tx*8;
        float4 o0, o1;
        o0.x = acc[i][0]+bias[0]; o0.y = acc[i][1]+bias[1];
        o0.z = acc[i][2]+bias[2]; o0.w = acc[i][3]+bias[3];
        o1.x = acc[i][4]+bias[4]; o1.y = acc[i][5]+bias[5];
        o1.z = acc[i][6]+bias[6]; o1.w = acc[i][7]+bias[7];
        *(float4*)orow = o0;
        *(float4*)(orow + 4) = o1;
    }
}

// ---------------------------------------------------------------- K2: weight-stationary LSTM
// 256 WGs: member m = blockIdx>>6 (64-unit slice), group g = blockIdx&63.
// Group members at blockIdx {g,64+g,128+g,192+g} -> same value mod 8 -> same XCD (perf hint).
// Thread (kg=tid>>7, rp=tid&127): rows {2rp,2rp+1} x k[kg*32,+32) of local slice in VGPRs.
__global__ __launch_bounds__(1024)
__attribute__((amdgpu_waves_per_eu(4, 4)))
void k2_lstm(
    const float* __restrict__ whh_f, const float* __restrict__ whh_b,
    const float* __restrict__ xg, float* __restrict__ hcat,
    float* __restrict__ hx, unsigned int* __restrict__ flags)
{
    const int m = blockIdx.x >> 6;       // slice / member 0..3
    const int g = blockIdx.x & 63;       // group
    const int dir = g >> 5;
    const int b0 = (g & 31) * 2;
    const float* __restrict__ w = dir ? whh_b : whh_f;

    const int tid = threadIdx.x;
    const int kg = tid >> 7;             // 0..7, wave-uniform
    const int rp = tid & 127;
    const int r0 = rp * 2;               // local gate-row pair base (r = gate*64+u)
    const int gate = r0 >> 6;            // 0..3
    const int u0 = r0 & 63;              // unit of row0; row1 = u0+1 (same gate)
    const int kbase = kg * 32;

    // ---- weights to VGPRs (plain loads), then pin with asm value barriers
    float4 w0[8], w1[8];
    {
        const float* wp0 = w + (size_t)(gate * 256 + m * 64 + u0) * 256 + kbase;
        const float* wp1 = wp0 + 256;
        #pragma unroll
        for (int i = 0; i < 8; ++i) {
            w0[i] = *(const float4*)(wp0 + i * 4);
            w1[i] = *(const float4*)(wp1 + i * 4);
        }
    }
    #pragma unroll
    for (int i = 0; i < 8; ++i) {
        asm volatile("" : "+v"(w0[i].x), "+v"(w0[i].y), "+v"(w0[i].z), "+v"(w0[i].w));
        asm volatile("" : "+v"(w1[i].x), "+v"(w1[i].y), "+v"(w1[i].z), "+v"(w1[i].w));
    }

    __shared__ __align__(16) float hs[2][256];
    __shared__ float cs[2][64];
    __shared__ __align__(16) float red[8][2][256];

    if (tid < 512) hs[tid >> 8][tid & 255] = 0.f;
    if (tid < 128) cs[tid >> 6][tid & 63] = 0.f;

    // BC mapping (tid<128): (s_c, ul)
    const int s_c = tid >> 6, ul = tid & 63;
    const float* xgp = xg + (size_t)(dir * 64 + b0 + s_c) * 262144 + m * 64 + ul;
    float* hx_w = hx + ((size_t)g * 2 + s_c) * 256 + m * 64 + ul;        // + buf*32768
    // loader mapping (tid<256)
    const int s_r = tid >> 7, pr = tid & 127;
    const ull* hx_r = (const ull*)hx + ((size_t)g * 2 + s_r) * 128 + pr; // + buf*16384
    float* hc_r = hcat + (size_t)(b0 + s_r) * 131072 + dir * 256 + 2 * pr;
    // hcat-writer mapping (tid in [512,768))
    const int tid2 = tid & 255;
    const int s_h = tid2 >> 7, pr2 = tid2 & 127;
    const ull* hx_h = (const ull*)hx + ((size_t)g * 2 + s_h) * 128 + pr2;
    float* hc_h = hcat + (size_t)(b0 + s_h) * 131072 + dir * 256 + 2 * pr2;

    unsigned int* myflag = flags + ((size_t)g * 4 + m) * 16;

    __syncthreads();

    for (int t = 0; t < 256; ++t) {
        // prefetch xg gate values (BC threads), hidden under phase A
        float xp0 = 0.f, xp1 = 0.f, xp2 = 0.f, xp3 = 0.f;
        if (tid < 128) {
            const float* xq = xgp + (size_t)t * 1024;
            xp0 = xq[0]; xp1 = xq[256]; xp2 = xq[512]; xp3 = xq[768];
        }

        // ---- phase A: partial gates from register-resident weights
        float a00 = 0.f, a01 = 0.f, a10 = 0.f, a11 = 0.f;
        #pragma unroll
        for (int i = 0; i < 8; ++i) {
            float4 ha = *(const float4*)&hs[0][kbase + i * 4];   // broadcast read
            float4 hb = *(const float4*)&hs[1][kbase + i * 4];
            float4 wa = w0[i], wb = w1[i];
            a00 += wa.x*ha.x + wa.y*ha.y + wa.z*ha.z + wa.w*ha.w;
            a01 += wa.x*hb.x + wa.y*hb.y + wa.z*hb.z + wa.w*hb.w;
            a10 += wb.x*ha.x + wb.y*ha.y + wb.z*ha.z + wb.w*ha.w;
            a11 += wb.x*hb.x + wb.y*hb.y + wb.z*hb.z + wb.w*hb.w;
        }
        *(float2*)&red[kg][0][r0] = make_float2(a00, a10);
        *(float2*)&red[kg][1][r0] = make_float2(a01, a11);
        __syncthreads();                                  // b1

        // ---- phase BC: k-reduction + cell update + publish own slice
        if (tid < 128) {
            float gi = xp0, gf = xp1, gg = xp2, go = xp3;
            #pragma unroll
            for (int kk = 0; kk < 8; ++kk) {
                gi += red[kk][s_c][ul];
                gf += red[kk][s_c][64 + ul];
                gg += red[kk][s_c][128 + ul];
                go += red[kk][s_c][192 + ul];
            }
            float si = 1.f / (1.f + expf(-gi));
            float sf = 1.f / (1.f + expf(-gf));
            float so = 1.f / (1.f + expf(-go));
            float cn = sf * cs[s_c][ul] + si * tanhf(gg);
            float hn = so * tanhf(cn);
            cs[s_c][ul] = cn;
            hs[s_c][m * 64 + ul] = hn;
            __hip_atomic_store(hx_w + (t & 1) * 32768, hn,
                               __ATOMIC_RELAXED, __HIP_MEMORY_SCOPE_AGENT);
        }
        __syncthreads();                                  // b2 (drains hx stores)

        // ---- flag publish + 3-way spin; hcat(t-1) written by idle waves in parallel
        if (tid == 0)
            __hip_atomic_store(myflag, (unsigned)(t + 1),
                               __ATOMIC_RELEASE, __HIP_MEMORY_SCOPE_AGENT);
        if (tid < 4 && tid != m) {
            const unsigned int* pf = flags + ((size_t)g * 4 + tid) * 16;
            while (__hip_atomic_load(pf, __ATOMIC_RELAXED, __HIP_MEMORY_SCOPE_AGENT)
                   < (unsigned)(t + 1)) {}
        }
        if (t > 0 && (tid & 0x300) == 0x200) {           // tid in [512,768)
            ull dv = __hip_atomic_load(hx_h + ((t - 1) & 1) * 16384,
                                       __ATOMIC_RELAXED, __HIP_MEMORY_SCOPE_AGENT);
            union { ull u; float2 f; } cv; cv.u = dv;
            *(float2*)(hc_h + (size_t)(t - 1) * 512) = cv.f;
        }
        __syncthreads();                                  // b3

        // ---- loader: gather full h for next step
        if (tid < 256) {
            ull dv = __hip_atomic_load(hx_r + (t & 1) * 16384,
                                       __ATOMIC_RELAXED, __HIP_MEMORY_SCOPE_AGENT);
            union { ull u; float2 f; } cv; cv.u = dv;
            *(float2*)&hs[s_r][2 * pr] = cv.f;
        }
        __syncthreads();                                  // b4
    }

    // flush hcat(255) from final hs
    if (tid < 256) {
        float2 hv = *(float2*)&hs[s_r][2 * pr];
        *(float2*)(hc_r + (size_t)255 * 512) = hv;
    }
}

// ---------------------------------------------------------------- K3: emissions
__global__ __launch_bounds__(256) void k3_emis(
    const float* __restrict__ hcat, const float* __restrict__ wout,
    const float* __restrict__ bout, const int* __restrict__ lens,
    float* __restrict__ em)
{
    const int b = blockIdx.x >> 3;
    const int tt0 = (blockIdx.x & 7) * 32;
    __shared__ float wsw[512 * 32];
    const int tid = threadIdx.x;
    for (int i = tid; i < 16384; i += 256) {
        int c_ = i >> 9, k_ = i & 511;
        wsw[k_ * 32 + ((k_ + c_) & 31)] = wout[i];
    }
    __syncthreads();
    const int c = tid & 31, tq = tid >> 5;
    const int L = lens[b];
    float acc[4];
    const float* hfp[4];
    const float* hbp[4];
    int tv[4];
    #pragma unroll
    for (int i = 0; i < 4; ++i) {
        int t = tt0 + i * 8 + tq;
        tv[i] = t;
        int tr = (t < L) ? (L - 1 - t) : t;
        hfp[i] = hcat + ((size_t)b * 256 + t) * 512;
        hbp[i] = hcat + ((size_t)b * 256 + tr) * 512 + 256;
        acc[i] = bout[c];
    }
    for (int k = 0; k < 256; k += 4) {
        float w0 = wsw[(k+0)*32 + ((k+0+c)&31)];
        float w1 = wsw[(k+1)*32 + ((k+1+c)&31)];
        float w2_ = wsw[(k+2)*32 + ((k+2+c)&31)];
        float w3 = wsw[(k+3)*32 + ((k+3+c)&31)];
        #pragma unroll
        for (int i = 0; i < 4; ++i) {
            float4 h = *(const float4*)(hfp[i] + k);
            acc[i] += h.x*w0 + h.y*w1 + h.z*w2_ + h.w*w3;
        }
        float v0 = wsw[(256+k+0)*32 + ((256+k+0+c)&31)];
        float v1 = wsw[(256+k+1)*32 + ((256+k+1+c)&31)];
        float v2 = wsw[(256+k+2)*32 + ((256+k+2+c)&31)];
        float v3 = wsw[(256+k+3)*32 + ((256+k+3+c)&31)];
        #pragma unroll
        for (int i = 0; i < 4; ++i) {
            float4 h = *(const float4*)(hbp[i] + k);
            acc[i] += h.x*v0 + h.y*v1 + h.z*v2 + h.w*v3;
        }
    }
    #pragma unroll
    for (int i = 0; i < 4; ++i)
        em[((size_t)b * 256 + tv[i]) * 32 + c] = acc[i];
}

// ---------------------------------------------------------------- K4: Viterbi fwd + backtrace
__global__ __launch_bounds__(256) void k4_viterbi(
    const float* __restrict__ em, const int* __restrict__ lens,
    const float* __restrict__ strans, const float* __restrict__ etrans,
    const float* __restrict__ trans, float* __restrict__ out)
{
    const int b = blockIdx.x;
    __shared__ float em_s[8192];
    __shared__ float trans_t[32 * 33];
    __shared__ float score_s[32];
    __shared__ float fin[32];
    __shared__ unsigned char hist[256][32];
    __shared__ unsigned char path[256];
    __shared__ float bs_s;
    const int tid = threadIdx.x;
    for (int i = tid; i < 8192; i += 256) em_s[i] = em[(size_t)b * 8192 + i];
    for (int i = tid; i < 1024; i += 256) {
        int p = i >> 5, cc = i & 31;
        trans_t[cc * 33 + p] = trans[i];
    }
    __syncthreads();
    if (tid < 32) score_s[tid] = strans[tid] + em_s[tid];
    __syncthreads();
    const int c = tid >> 3, pg = tid & 7;
    const int L = lens[b];
    for (int t = 1; t < 256; ++t) {
        float v = -1e30f; int bi = 0;
        #pragma unroll
        for (int i = 0; i < 4; ++i) {
            int p = pg * 4 + i;
            float cand = score_s[p] + trans_t[c * 33 + p];
            if (cand > v) { v = cand; bi = p; }
        }
        #pragma unroll
        for (int off = 4; off >= 1; off >>= 1) {
            float ov = __shfl_down(v, off);
            int oi = __shfl_down(bi, off);
            if (ov > v) { v = ov; bi = oi; }
        }
        float ns = 0.f;
        if (pg == 0) {
            hist[t][c] = (unsigned char)bi;
            ns = (t < L) ? (v + em_s[t * 32 + c]) : score_s[c];
        }
        __syncthreads();
        if (pg == 0) score_s[c] = ns;
        __syncthreads();
    }
    if (tid < 32) fin[tid] = score_s[tid] + etrans[tid];
    __syncthreads();
    if (tid == 0) {
        float bv = -1e30f; int bl = 0;
        for (int cc = 0; cc < 32; ++cc)
            if (fin[cc] > bv) { bv = fin[cc]; bl = cc; }
        bs_s = bv;
        int tag = bl;
        path[255] = (unsigned char)tag;
        for (int t = 254; t >= 0; --t) {
            if (t < L - 1) tag = hist[t + 1][tag];
            path[t] = (unsigned char)tag;
        }
    }
    __syncthreads();
    out[(size_t)b * 256 + tid] = (float)path[tid];
    if (tid == 0) out[16384 + b] = bs_s;
}

// ---------------------------------------------------------------- launch
extern "C" void kernel_launch(void* const* d_in, const int* in_sizes, int n_in,
                              void* d_out, int out_size, void* d_ws, size_t ws_size,
                              hipStream_t stream)
{
    const int*   sent   = (const int*)  d_in[0];
    const int*   lens   = (const int*)  d_in[1];
    const float* emb    = (const float*)d_in[2];
    const float* wih_f  = (const float*)d_in[3];
    const float* whh_f  = (const float*)d_in[4];
    const float* bih_f  = (const float*)d_in[5];
    const float* bhh_f  = (const float*)d_in[6];
    const float* wih_b  = (const float*)d_in[7];
    const float* whh_b  = (const float*)d_in[8];
    const float* bih_b  = (const float*)d_in[9];
    const float* bhh_b  = (const float*)d_in[10];
    const float* wout   = (const float*)d_in[11];
    const float* bout   = (const float*)d_in[12];
    const float* strans = (const float*)d_in[13];
    const float* etrans = (const float*)d_in[14];
    const float* trans  = (const float*)d_in[15];
    float* out = (float*)d_out;

    float* ws   = (float*)d_ws;
    float* xg   = ws;                        // 33554432
    float* hcat = xg + 33554432;             // 8388608
    float* em   = hcat + 8388608;            // 524288
    float* hx   = em + 524288;               // 65536
    unsigned int* flags = (unsigned int*)(hx + 65536);  // 4096

    hipLaunchKernelGGL(k0z_zero, dim3(4), dim3(1024), 0, stream, flags);
    hipLaunchKernelGGL(k1_xgemm, dim3(2048), dim3(256), 0, stream,
                       sent, lens, emb, wih_f, wih_b, bih_f, bhh_f, bih_b, bhh_b, xg);
    hipLaunchKernelGGL(k2_lstm, dim3(256), dim3(1024), 0, stream,
                       whh_f, whh_b, xg, hcat, hx, flags);
    hipLaunchKernelGGL(k3_emis, dim3(512), dim3(256), 0, stream,
                       hcat, wout, bout, lens, em);
    hipLaunchKernelGGL(k4_viterbi, dim3(64), dim3(256), 0, stream,
                       em, lens, strans, etrans, trans, out);
}